// Round 1
// baseline (432.802 us; speedup 1.0000x reference)
//
#include <hip/hip_runtime.h>
#include <hip/hip_bf16.h>
#include <math.h>

#define SEQ 2048
#define HID 1024
#define NH 16
#define HD 64

using f32x4  = __attribute__((ext_vector_type(4))) float;
using bf16x8 = __attribute__((ext_vector_type(8))) short;

__device__ __forceinline__ short f2bf(float f) {
  unsigned int x = __float_as_uint(f);
  unsigned int r = (x + 0x7fffu + ((x >> 16) & 1u)) >> 16;
  return (short)(r & 0xffffu);
}

__device__ __forceinline__ void async_cp16(const void* g, void* l) {
  // 16B per lane, LDS dest = wave-uniform base + lane*16
  __builtin_amdgcn_global_load_lds(
      (__attribute__((address_space(1))) void*)(g),
      (__attribute__((address_space(3))) void*)(l), 16, 0, 0);
}

// ---------------- fp32 -> bf16 weight conversion ----------------
__global__ void cvt_bf16_kernel(const float* __restrict__ in, short* __restrict__ out, int n4) {
  int i = blockIdx.x * blockDim.x + threadIdx.x;
  if (i < n4) {
    float4 v = ((const float4*)in)[i];
    short4 o;
    o.x = f2bf(v.x); o.y = f2bf(v.y); o.z = f2bf(v.z); o.w = f2bf(v.w);
    ((short4*)out)[i] = o;
  }
}

// ---------------- LayerNorm (row per block) ----------------
__global__ __launch_bounds__(256) void ln_kernel(const float* __restrict__ x,
    const float* __restrict__ w, const float* __restrict__ b, short* __restrict__ out) {
  int row = blockIdx.x;
  int tid = threadIdx.x;
  float4 v = ((const float4*)(x + (size_t)row * HID))[tid];
  float s  = v.x + v.y + v.z + v.w;
  float s2 = v.x*v.x + v.y*v.y + v.z*v.z + v.w*v.w;
#pragma unroll
  for (int o = 32; o >= 1; o >>= 1) {
    s  += __shfl_xor(s,  o);
    s2 += __shfl_xor(s2, o);
  }
  __shared__ float red[8];
  int wv = tid >> 6;
  if ((tid & 63) == 0) { red[wv] = s; red[4 + wv] = s2; }
  __syncthreads();
  float ts  = red[0] + red[1] + red[2] + red[3];
  float ts2 = red[4] + red[5] + red[6] + red[7];
  float mean = ts * (1.0f / HID);
  float var  = ts2 * (1.0f / HID) - mean * mean;
  float rs = rsqrtf(var + 1e-5f);
  float4 wv4 = ((const float4*)w)[tid];
  float4 bv4 = ((const float4*)b)[tid];
  short4 o;
  o.x = f2bf((v.x - mean) * rs * wv4.x + bv4.x);
  o.y = f2bf((v.y - mean) * rs * wv4.y + bv4.y);
  o.z = f2bf((v.z - mean) * rs * wv4.z + bv4.z);
  o.w = f2bf((v.w - mean) * rs * wv4.w + bv4.w);
  ((short4*)(out + (size_t)row * HID))[tid] = o;
}

// ---------------- RoPE on q,k + split to (head, seq, hd) bf16 ----------------
__global__ void rope_qk_kernel(const float* __restrict__ qkv,
    const float* __restrict__ cosb, const float* __restrict__ sinb,
    short* __restrict__ Qh, short* __restrict__ Kh) {
  int tid = blockIdx.x * blockDim.x + threadIdx.x;  // s*1024 + j*512 + h*32 + i
  int s   = tid >> 10;
  int r   = tid & 1023;
  int j   = r >> 9;
  int rem = r & 511;
  int h   = rem >> 5;
  int i   = rem & 31;
  int d   = i * 2;
  float2 ab = *(const float2*)(qkv + (size_t)s * 3072 + j * 1024 + h * 64 + d);
  float c  = cosb[s * 32 + i];
  float sn = sinb[s * 32 + i];
  short2 o;
  o.x = f2bf(ab.x * c - ab.y * sn);
  o.y = f2bf(ab.x * sn + ab.y * c);
  short* dst = (j == 0 ? Qh : Kh) + ((size_t)h * SEQ + s) * HD + d;
  *(short2*)dst = o;
}

// ---------------- V transpose to (head, hd, seq) bf16 ----------------
__global__ void vtrans_kernel(const float* __restrict__ qkv, short* __restrict__ Vt) {
  int tid  = blockIdx.x * blockDim.x + threadIdx.x;  // (h*64+d)*2048 + s
  int hd_i = tid >> 11;
  int s    = tid & 2047;
  float v = qkv[(size_t)s * 3072 + 2048 + hd_i];
  Vt[(size_t)hd_i * SEQ + s] = f2bf(v);
}

// ---------------- GEMM: C(MxN) = A(MxK) * B(NxK)^T, bf16 MFMA ----------------
// EPI 0: float out = acc + bias
// EPI 1: float out = acc + bias + resid
// EPI 2: bf16 out  = gelu_tanh(acc + bias)
template <int EPI>
__global__ __launch_bounds__(256) void gemm_bt_kernel(
    const short* __restrict__ A, const short* __restrict__ B,
    const float* __restrict__ bias, const float* __restrict__ resid,
    void* __restrict__ outp, int M, int N, int K) {
  __shared__ __attribute__((aligned(16))) short Alds[128 * 32];
  __shared__ __attribute__((aligned(16))) short Blds[128 * 32];
  int tid = threadIdx.x;
  int w    = tid >> 6;
  int lane = tid & 63;
  int lcol  = lane & 15;
  int lhalf = lane >> 4;
  int m0 = blockIdx.y * 128;
  int n0 = blockIdx.x * 128;
  int wm = (w & 1) * 64;
  int wn = (w >> 1) * 64;
  f32x4 acc[4][4];
#pragma unroll
  for (int i = 0; i < 4; i++)
#pragma unroll
    for (int j = 0; j < 4; j++) acc[i][j] = (f32x4){0.f, 0.f, 0.f, 0.f};

  for (int k0 = 0; k0 < K; k0 += 32) {
#pragma unroll
    for (int p = 0; p < 2; p++) {
      int seg = p * 256 + tid;
      async_cp16(A + (size_t)(m0 + (seg >> 2)) * K + k0 + (seg & 3) * 8,
                 Alds + p * 2048 + w * 512);
      async_cp16(B + (size_t)(n0 + (seg >> 2)) * K + k0 + (seg & 3) * 8,
                 Blds + p * 2048 + w * 512);
    }
    __syncthreads();
    bf16x8 af[4], bfr[4];
#pragma unroll
    for (int i = 0; i < 4; i++)
      af[i] = *(const bf16x8*)(Alds + (wm + i * 16 + lcol) * 32 + lhalf * 8);
#pragma unroll
    for (int j = 0; j < 4; j++)
      bfr[j] = *(const bf16x8*)(Blds + (wn + j * 16 + lcol) * 32 + lhalf * 8);
#pragma unroll
    for (int i = 0; i < 4; i++)
#pragma unroll
      for (int j = 0; j < 4; j++)
        acc[i][j] = __builtin_amdgcn_mfma_f32_16x16x32_bf16(af[i], bfr[j], acc[i][j], 0, 0, 0);
    __syncthreads();
  }

#pragma unroll
  for (int i = 0; i < 4; i++) {
#pragma unroll
    for (int j = 0; j < 4; j++) {
#pragma unroll
      for (int r = 0; r < 4; r++) {
        int row = m0 + wm + i * 16 + lhalf * 4 + r;
        int col = n0 + wn + j * 16 + lcol;
        float v = acc[i][j][r] + bias[col];
        if (EPI == 1) v += resid[(size_t)row * N + col];
        if (EPI == 2) {
          float t = 0.7978845608028654f * (v + 0.044715f * v * v * v);
          v = 0.5f * v * (1.0f + tanhf(t));
          ((short*)outp)[(size_t)row * N + col] = f2bf(v);
        } else {
          ((float*)outp)[(size_t)row * N + col] = v;
        }
      }
    }
  }
}

// ---------------- Flash attention with segment bias ----------------
// scores = (q.k)/8 + (seg_q==seg_t ? 1 : 0); softmax over ALL t (bias, not mask)
__global__ __launch_bounds__(256) void attn_kernel(
    const short* __restrict__ Qh, const short* __restrict__ Kh,
    const short* __restrict__ Vt, const int* __restrict__ offs,
    short* __restrict__ out) {
  __shared__ __attribute__((aligned(16))) short Klds[32 * 64];
  __shared__ __attribute__((aligned(16))) short Vlds[64 * 32];
  __shared__ __attribute__((aligned(16))) short Plds[4 * 16 * 32];
  int head = blockIdx.y;
  int q0   = blockIdx.x * 64;
  int tid  = threadIdx.x;
  int w    = tid >> 6;
  int lane = tid & 63;
  int lcol  = lane & 15;
  int lhalf = lane >> 4;
  int off1 = offs[1], off2 = offs[2], off3 = offs[3];

  int qrow = q0 + w * 16 + lcol;
  const short* qb = Qh + ((size_t)head * SEQ + qrow) * HD + lhalf * 8;
  bf16x8 qf0 = *(const bf16x8*)(qb);
  bf16x8 qf1 = *(const bf16x8*)(qb + 32);

  int sq[4];
#pragma unroll
  for (int r = 0; r < 4; r++) {
    int qr = q0 + w * 16 + lhalf * 4 + r;
    sq[r] = (qr >= off1) + (qr >= off2) + (qr >= off3);
  }
  float m_i[4], l_i[4];
  f32x4 o_acc[4];
#pragma unroll
  for (int r = 0; r < 4; r++) { m_i[r] = -1e30f; l_i[r] = 0.f; }
#pragma unroll
  for (int nt = 0; nt < 4; nt++) o_acc[nt] = (f32x4){0.f, 0.f, 0.f, 0.f};

  for (int t0 = 0; t0 < SEQ; t0 += 32) {
    async_cp16(Kh + ((size_t)head * SEQ + t0 + (tid >> 3)) * HD + (tid & 7) * 8,
               Klds + w * 512);
    async_cp16(Vt + ((size_t)head * HD + (tid >> 2)) * SEQ + t0 + (tid & 3) * 8,
               Vlds + w * 512);
    __syncthreads();

    f32x4 sacc[2];
#pragma unroll
    for (int n = 0; n < 2; n++) {
      const short* kb = Klds + (n * 16 + lcol) * 64 + lhalf * 8;
      bf16x8 kf0 = *(const bf16x8*)kb;
      bf16x8 kf1 = *(const bf16x8*)(kb + 32);
      f32x4 a = (f32x4){0.f, 0.f, 0.f, 0.f};
      a = __builtin_amdgcn_mfma_f32_16x16x32_bf16(qf0, kf0, a, 0, 0, 0);
      a = __builtin_amdgcn_mfma_f32_16x16x32_bf16(qf1, kf1, a, 0, 0, 0);
      sacc[n] = a;
    }

    float sv[2][4];
#pragma unroll
    for (int n = 0; n < 2; n++) {
      int tc = t0 + n * 16 + lcol;
      int st = (tc >= off1) + (tc >= off2) + (tc >= off3);
#pragma unroll
      for (int r = 0; r < 4; r++)
        sv[n][r] = sacc[n][r] * 0.125f + ((st == sq[r]) ? 1.0f : 0.0f);
    }
    float alpha[4];
#pragma unroll
    for (int r = 0; r < 4; r++) {
      float mx = fmaxf(sv[0][r], sv[1][r]);
#pragma unroll
      for (int o = 8; o >= 1; o >>= 1) mx = fmaxf(mx, __shfl_xor(mx, o));
      float mnew = fmaxf(m_i[r], mx);
      alpha[r] = __expf(m_i[r] - mnew);
      float p0 = __expf(sv[0][r] - mnew);
      float p1 = __expf(sv[1][r] - mnew);
      sv[0][r] = p0; sv[1][r] = p1;
      float ps = p0 + p1;
#pragma unroll
      for (int o = 8; o >= 1; o >>= 1) ps += __shfl_xor(ps, o);
      l_i[r] = l_i[r] * alpha[r] + ps;
      m_i[r] = mnew;
    }
#pragma unroll
    for (int nt = 0; nt < 4; nt++)
#pragma unroll
      for (int r = 0; r < 4; r++) o_acc[nt][r] *= alpha[r];

    // P (C-layout) -> LDS -> A-layout frag (per-wave region, no block barrier)
    short* pb = Plds + w * 512;
#pragma unroll
    for (int n = 0; n < 2; n++)
#pragma unroll
      for (int r = 0; r < 4; r++)
        pb[(lhalf * 4 + r) * 32 + n * 16 + lcol] = f2bf(sv[n][r]);
    bf16x8 pf = *(const bf16x8*)(pb + lcol * 32 + lhalf * 8);
#pragma unroll
    for (int nt = 0; nt < 4; nt++) {
      bf16x8 vf = *(const bf16x8*)(Vlds + (nt * 16 + lcol) * 32 + lhalf * 8);
      o_acc[nt] = __builtin_amdgcn_mfma_f32_16x16x32_bf16(pf, vf, o_acc[nt], 0, 0, 0);
    }
    __syncthreads();
  }

#pragma unroll
  for (int nt = 0; nt < 4; nt++) {
#pragma unroll
    for (int r = 0; r < 4; r++) {
      int row = q0 + w * 16 + lhalf * 4 + r;
      out[(size_t)row * HID + head * HD + nt * 16 + lcol] = f2bf(o_acc[nt][r] / l_i[r]);
    }
  }
}

extern "C" void kernel_launch(void* const* d_in, const int* in_sizes, int n_in,
                              void* d_out, int out_size, void* d_ws, size_t ws_size,
                              hipStream_t stream) {
  const float* x      = (const float*)d_in[0];
  const float* ropec  = (const float*)d_in[1];
  const float* ropes  = (const float*)d_in[2];
  const float* n0w    = (const float*)d_in[3];
  const float* n0b    = (const float*)d_in[4];
  const float* n1w    = (const float*)d_in[5];
  const float* n1b    = (const float*)d_in[6];
  const float* wqkv_w = (const float*)d_in[7];
  const float* wqkv_b = (const float*)d_in[8];
  const float* wo_w   = (const float*)d_in[9];
  const float* wo_b   = (const float*)d_in[10];
  const float* up_w   = (const float*)d_in[11];
  const float* up_b   = (const float*)d_in[12];
  const float* down_w = (const float*)d_in[13];
  const float* down_b = (const float*)d_in[14];
  const int*   offs   = (const int*)d_in[15];
  float* out = (float*)d_out;

  char* p = (char*)d_ws;
  auto alloc = [&](size_t bytes) {
    char* r = p;
    p += (bytes + 255) & ~(size_t)255;
    return r;
  };
  short* wqkv_bf = (short*)alloc((size_t)3072 * 1024 * 2);
  short* wo_bf   = (short*)alloc((size_t)1024 * 1024 * 2);
  short* up_bf   = (short*)alloc((size_t)4096 * 1024 * 2);
  short* down_bf = (short*)alloc((size_t)4096 * 1024 * 2);
  short* h0      = (short*)alloc((size_t)2048 * 1024 * 2);
  float* qkv     = (float*)alloc((size_t)2048 * 3072 * 4);
  short* Qh      = (short*)alloc((size_t)2048 * 1024 * 2);
  short* Kh      = (short*)alloc((size_t)2048 * 1024 * 2);
  short* Vt      = (short*)alloc((size_t)2048 * 1024 * 2);
  short* attn    = (short*)alloc((size_t)2048 * 1024 * 2);
  float* x1      = (float*)alloc((size_t)2048 * 1024 * 4);
  short* h1      = (short*)alloc((size_t)2048 * 1024 * 2);
  short* u       = (short*)alloc((size_t)2048 * 4096 * 2);

  cvt_bf16_kernel<<<3072, 256, 0, stream>>>(wqkv_w, wqkv_bf, 3072 * 1024 / 4);
  cvt_bf16_kernel<<<1024, 256, 0, stream>>>(wo_w, wo_bf, 1024 * 1024 / 4);
  cvt_bf16_kernel<<<4096, 256, 0, stream>>>(up_w, up_bf, 4096 * 1024 / 4);
  cvt_bf16_kernel<<<4096, 256, 0, stream>>>(down_w, down_bf, 4096 * 1024 / 4);

  ln_kernel<<<2048, 256, 0, stream>>>(x, n0w, n0b, h0);
  gemm_bt_kernel<0><<<dim3(24, 16), 256, 0, stream>>>(h0, wqkv_bf, wqkv_b, nullptr, qkv, 2048, 3072, 1024);
  rope_qk_kernel<<<8192, 256, 0, stream>>>(qkv, ropec, ropes, Qh, Kh);
  vtrans_kernel<<<8192, 256, 0, stream>>>(qkv, Vt);
  attn_kernel<<<dim3(32, 16), 256, 0, stream>>>(Qh, Kh, Vt, offs, attn);
  gemm_bt_kernel<1><<<dim3(8, 16), 256, 0, stream>>>(attn, wo_bf, wo_b, x, x1, 2048, 1024, 1024);
  ln_kernel<<<2048, 256, 0, stream>>>(x1, n1w, n1b, h1);
  gemm_bt_kernel<2><<<dim3(32, 16), 256, 0, stream>>>(h1, up_bf, up_b, nullptr, u, 2048, 4096, 1024);
  gemm_bt_kernel<1><<<dim3(8, 16), 256, 0, stream>>>(u, down_bf, down_b, x1, out, 2048, 1024, 4096);
}

// Round 2
// 366.098 us; speedup vs baseline: 1.1822x; 1.1822x over previous
//
#include <hip/hip_runtime.h>
#include <hip/hip_bf16.h>
#include <math.h>

#define SEQ 2048
#define HID 1024
#define NH 16
#define HD 64

using f32x4  = __attribute__((ext_vector_type(4))) float;
using bf16x8 = __attribute__((ext_vector_type(8))) short;

union U8 { unsigned int u[4]; bf16x8 v; short s[8]; };

__device__ __forceinline__ short f2bf(float f) {
  unsigned int x = __float_as_uint(f);
  unsigned int r = (x + 0x7fffu + ((x >> 16) & 1u)) >> 16;
  return (short)(r & 0xffffu);
}

__device__ __forceinline__ unsigned int pkbf(float a, float b) {
  return ((unsigned int)(unsigned short)f2bf(a)) |
         (((unsigned int)(unsigned short)f2bf(b)) << 16);
}

__device__ __forceinline__ void async_cp16(const void* g, void* l) {
  // 16B per lane, LDS dest = wave-uniform base + lane*16
  __builtin_amdgcn_global_load_lds(
      (__attribute__((address_space(1))) void*)(g),
      (__attribute__((address_space(3))) void*)(l), 16, 0, 0);
}

// ---------------- fp32 -> bf16 weight conversion ----------------
__global__ void cvt_bf16_kernel(const float* __restrict__ in, short* __restrict__ out, int n4) {
  int i = blockIdx.x * blockDim.x + threadIdx.x;
  if (i < n4) {
    float4 v = ((const float4*)in)[i];
    short4 o;
    o.x = f2bf(v.x); o.y = f2bf(v.y); o.z = f2bf(v.z); o.w = f2bf(v.w);
    ((short4*)out)[i] = o;
  }
}

// ---------------- LayerNorm (row per block) ----------------
__global__ __launch_bounds__(256) void ln_kernel(const float* __restrict__ x,
    const float* __restrict__ w, const float* __restrict__ b, short* __restrict__ out) {
  int row = blockIdx.x;
  int tid = threadIdx.x;
  float4 v = ((const float4*)(x + (size_t)row * HID))[tid];
  float s  = v.x + v.y + v.z + v.w;
  float s2 = v.x*v.x + v.y*v.y + v.z*v.z + v.w*v.w;
#pragma unroll
  for (int o = 32; o >= 1; o >>= 1) {
    s  += __shfl_xor(s,  o);
    s2 += __shfl_xor(s2, o);
  }
  __shared__ float red[8];
  int wv = tid >> 6;
  if ((tid & 63) == 0) { red[wv] = s; red[4 + wv] = s2; }
  __syncthreads();
  float ts  = red[0] + red[1] + red[2] + red[3];
  float ts2 = red[4] + red[5] + red[6] + red[7];
  float mean = ts * (1.0f / HID);
  float var  = ts2 * (1.0f / HID) - mean * mean;
  float rs = rsqrtf(var + 1e-5f);
  float4 wv4 = ((const float4*)w)[tid];
  float4 bv4 = ((const float4*)b)[tid];
  short4 o;
  o.x = f2bf((v.x - mean) * rs * wv4.x + bv4.x);
  o.y = f2bf((v.y - mean) * rs * wv4.y + bv4.y);
  o.z = f2bf((v.z - mean) * rs * wv4.z + bv4.z);
  o.w = f2bf((v.w - mean) * rs * wv4.w + bv4.w);
  ((short4*)(out + (size_t)row * HID))[tid] = o;
}

// ---------------- RoPE on q,k + split to (head, seq, hd) bf16 ----------------
__global__ void rope_qk_kernel(const float* __restrict__ qkv,
    const float* __restrict__ cosb, const float* __restrict__ sinb,
    short* __restrict__ Qh, short* __restrict__ Kh) {
  int tid = blockIdx.x * blockDim.x + threadIdx.x;  // s*1024 + j*512 + h*32 + i
  int s   = tid >> 10;
  int r   = tid & 1023;
  int j   = r >> 9;
  int rem = r & 511;
  int h   = rem >> 5;
  int i   = rem & 31;
  int d   = i * 2;
  float2 ab = *(const float2*)(qkv + (size_t)s * 3072 + j * 1024 + h * 64 + d);
  float c  = cosb[s * 32 + i];
  float sn = sinb[s * 32 + i];
  short2 o;
  o.x = f2bf(ab.x * c - ab.y * sn);
  o.y = f2bf(ab.x * sn + ab.y * c);
  short* dst = (j == 0 ? Qh : Kh) + ((size_t)h * SEQ + s) * HD + d;
  *(short2*)dst = o;
}

// ---------------- V transpose to (head, hd, seq) bf16, LDS-tiled ----------------
__global__ __launch_bounds__(256) void vtrans_kernel(const float* __restrict__ qkv,
                                                     short* __restrict__ Vt) {
  __shared__ short tile[64 * 68];  // 64 s-rows x 64 d-cols, pad 68 (8B-aligned rows)
  int s0   = blockIdx.x * 64;
  int head = blockIdx.y;
  int tid  = threadIdx.x;
  int sl = tid >> 4;
  int c4 = tid & 15;
#pragma unroll
  for (int rr = 0; rr < 4; rr++) {
    int s = rr * 16 + sl;
    float4 v = *(const float4*)(qkv + (size_t)(s0 + s) * 3072 + 2048 + head * 64 + c4 * 4);
    short4 o;
    o.x = f2bf(v.x); o.y = f2bf(v.y); o.z = f2bf(v.z); o.w = f2bf(v.w);
    *(short4*)(tile + s * 68 + c4 * 4) = o;
  }
  __syncthreads();
#pragma unroll
  for (int p = 0; p < 2; p++) {
    int seg = p * 256 + tid;
    int d   = seg >> 3;
    int sc  = seg & 7;
    U8 o;
#pragma unroll
    for (int j = 0; j < 8; j++) o.s[j] = tile[(sc * 8 + j) * 68 + d];
    *(bf16x8*)(Vt + ((size_t)head * HD + d) * SEQ + s0 + sc * 8) = o.v;
  }
}

// ---------------- GEMM: C(MxN) = A(MxK) * B(NxK)^T, bf16 MFMA ----------------
template <int EPI>
__global__ __launch_bounds__(256) void gemm_bt_kernel(
    const short* __restrict__ A, const short* __restrict__ B,
    const float* __restrict__ bias, const float* __restrict__ resid,
    void* __restrict__ outp, int M, int N, int K) {
  __shared__ __attribute__((aligned(16))) short Alds[128 * 32];
  __shared__ __attribute__((aligned(16))) short Blds[128 * 32];
  int tid = threadIdx.x;
  int w    = tid >> 6;
  int lane = tid & 63;
  int lcol  = lane & 15;
  int lhalf = lane >> 4;
  int m0 = blockIdx.y * 128;
  int n0 = blockIdx.x * 128;
  int wm = (w & 1) * 64;
  int wn = (w >> 1) * 64;
  f32x4 acc[4][4];
#pragma unroll
  for (int i = 0; i < 4; i++)
#pragma unroll
    for (int j = 0; j < 4; j++) acc[i][j] = (f32x4){0.f, 0.f, 0.f, 0.f};

  for (int k0 = 0; k0 < K; k0 += 32) {
#pragma unroll
    for (int p = 0; p < 2; p++) {
      int seg = p * 256 + tid;
      async_cp16(A + (size_t)(m0 + (seg >> 2)) * K + k0 + (seg & 3) * 8,
                 Alds + p * 2048 + w * 512);
      async_cp16(B + (size_t)(n0 + (seg >> 2)) * K + k0 + (seg & 3) * 8,
                 Blds + p * 2048 + w * 512);
    }
    __syncthreads();
    bf16x8 af[4], bfr[4];
#pragma unroll
    for (int i = 0; i < 4; i++)
      af[i] = *(const bf16x8*)(Alds + (wm + i * 16 + lcol) * 32 + lhalf * 8);
#pragma unroll
    for (int j = 0; j < 4; j++)
      bfr[j] = *(const bf16x8*)(Blds + (wn + j * 16 + lcol) * 32 + lhalf * 8);
#pragma unroll
    for (int i = 0; i < 4; i++)
#pragma unroll
      for (int j = 0; j < 4; j++)
        acc[i][j] = __builtin_amdgcn_mfma_f32_16x16x32_bf16(af[i], bfr[j], acc[i][j], 0, 0, 0);
    __syncthreads();
  }

#pragma unroll
  for (int i = 0; i < 4; i++) {
#pragma unroll
    for (int j = 0; j < 4; j++) {
#pragma unroll
      for (int r = 0; r < 4; r++) {
        int row = m0 + wm + i * 16 + lhalf * 4 + r;
        int col = n0 + wn + j * 16 + lcol;
        float v = acc[i][j][r] + bias[col];
        if (EPI == 1) v += resid[(size_t)row * N + col];
        if (EPI == 2) {
          float t = 0.7978845608028654f * (v + 0.044715f * v * v * v);
          v = 0.5f * v * (1.0f + tanhf(t));
          ((short*)outp)[(size_t)row * N + col] = f2bf(v);
        } else {
          ((float*)outp)[(size_t)row * N + col] = v;
        }
      }
    }
  }
}

// ---------------- Attention (single-pass exp, no online softmax) ----------------
// S^T = K.Q^T via MFMA (lane: q=lcol, key=h*4+r); p=exp(s/8 - 2 + same_seg)
// l accumulated via ones-A-operand MFMA. K-split over blockIdx.z, fp32 partials.
__global__ __launch_bounds__(256) void attn_kernel(
    const short* __restrict__ Qh, const short* __restrict__ Kh,
    const short* __restrict__ Vt, const int* __restrict__ offs,
    float* __restrict__ Opart, float* __restrict__ Lpart) {
  __shared__ __attribute__((aligned(16))) short Klds[64 * 64];  // key-major, xor-swizzled 16B chunks
  __shared__ __attribute__((aligned(16))) short Vlds[64 * 64];  // d-major, xor-swizzled
  __shared__ __attribute__((aligned(16))) unsigned int Plds[4][16 * 34];  // per-wave, pad 34
  int head = blockIdx.y;
  int q0   = blockIdx.x * 64;
  int z    = blockIdx.z;
  int tid  = threadIdx.x;
  int w    = tid >> 6;
  int lane = tid & 63;
  int lcol = lane & 15;
  int h    = lane >> 4;

  int o0 = offs[0], o1 = offs[1], o2 = offs[2], o3 = offs[3], o4 = offs[4];
  int qrow = q0 + w * 16 + lcol;
  int sq = (qrow >= o1) + (qrow >= o2) + (qrow >= o3);
  int lo = sq == 0 ? o0 : (sq == 1 ? o1 : (sq == 2 ? o2 : o3));
  int hi = sq == 0 ? o1 : (sq == 1 ? o2 : (sq == 2 ? o3 : o4));

  // Q B-fragment: B[n=q][k=d], k chunks by h
  const short* qb = Qh + ((size_t)head * SEQ + qrow) * HD + h * 8;
  bf16x8 qf0 = *(const bf16x8*)(qb);
  bf16x8 qf1 = *(const bf16x8*)(qb + 32);

  bf16x8 ones;
#pragma unroll
  for (int i = 0; i < 8; i++) ones[i] = 0x3F80;  // bf16 1.0

  f32x4 o_acc[4];
#pragma unroll
  for (int nt = 0; nt < 4; nt++) o_acc[nt] = (f32x4){0.f, 0.f, 0.f, 0.f};
  f32x4 acc_l = (f32x4){0.f, 0.f, 0.f, 0.f};

  int tbeg = z * 1024;
  for (int t0 = tbeg; t0 < tbeg + 1024; t0 += 64) {
#pragma unroll
    for (int p = 0; p < 2; p++) {
      int seg = p * 256 + tid;
      int row = seg >> 3;
      int g   = (seg & 7) ^ (row & 7);  // xor-swizzle source chunk
      async_cp16(Kh + ((size_t)head * SEQ + t0 + row) * HD + g * 8,
                 Klds + p * 2048 + w * 512);
      async_cp16(Vt + ((size_t)head * HD + row) * SEQ + t0 + g * 8,
                 Vlds + p * 2048 + w * 512);
    }
    __syncthreads();

    // S^T tiles + exp + pack into per-wave Plds (q-row major, padded)
#pragma unroll
    for (int n = 0; n < 4; n++) {
      int krow = n * 16 + lcol;
      const short* ka = Klds + krow * 64;
      bf16x8 kf0 = *(const bf16x8*)(ka + ((h ^ (lcol & 7)) * 8));
      bf16x8 kf1 = *(const bf16x8*)(ka + (((4 + h) ^ (lcol & 7)) * 8));
      f32x4 sacc = (f32x4){0.f, 0.f, 0.f, 0.f};
      sacc = __builtin_amdgcn_mfma_f32_16x16x32_bf16(kf0, qf0, sacc, 0, 0, 0);
      sacc = __builtin_amdgcn_mfma_f32_16x16x32_bf16(kf1, qf1, sacc, 0, 0, 0);
      float pv[4];
#pragma unroll
      for (int r = 0; r < 4; r++) {
        int key = t0 + n * 16 + h * 4 + r;
        float bias = (key >= lo && key < hi) ? -1.0f : -2.0f;
        pv[r] = __expf(fmaf(sacc[r], 0.125f, bias));
      }
      uint2 pw;
      pw.x = pkbf(pv[0], pv[1]);
      pw.y = pkbf(pv[2], pv[3]);
      *(uint2*)&Plds[w][lcol * 34 + n * 8 + h * 2] = pw;
    }

    // PV: O^T[d][q] += V^T . P^T ; l via ones
#pragma unroll
    for (int kc = 0; kc < 2; kc++) {
      int base = lcol * 34 + kc * 16 + h * 4;
      uint2 a = *(const uint2*)&Plds[w][base];
      uint2 b = *(const uint2*)&Plds[w][base + 2];
      U8 pu;
      pu.u[0] = a.x; pu.u[1] = a.y; pu.u[2] = b.x; pu.u[3] = b.y;
#pragma unroll
      for (int nt = 0; nt < 4; nt++) {
        int vrow = nt * 16 + lcol;
        bf16x8 vf = *(const bf16x8*)(Vlds + vrow * 64 + (((kc * 4 + h) ^ (lcol & 7)) * 8));
        o_acc[nt] = __builtin_amdgcn_mfma_f32_16x16x32_bf16(vf, pu.v, o_acc[nt], 0, 0, 0);
      }
      acc_l = __builtin_amdgcn_mfma_f32_16x16x32_bf16(ones, pu.v, acc_l, 0, 0, 0);
    }
    __syncthreads();
  }

  // store fp32 partials (unnormalized) + l
  float* op = Opart + (size_t)z * SEQ * HID + (size_t)qrow * HID + head * HD + h * 4;
#pragma unroll
  for (int nt = 0; nt < 4; nt++)
    *(f32x4*)(op + nt * 16) = o_acc[nt];
  if (lane < 16)
    Lpart[((size_t)z * NH + head) * SEQ + qrow] = acc_l[0];
}

__global__ __launch_bounds__(256) void attn_merge_kernel(
    const float* __restrict__ Opart, const float* __restrict__ Lpart,
    short* __restrict__ attn) {
  int i = blockIdx.x * blockDim.x + threadIdx.x;  // per float4, SEQ*HID/4
  int col4 = i & 255;
  int row  = i >> 8;
  int head = col4 >> 4;
  float4 a = ((const float4*)Opart)[i];
  float4 b = ((const float4*)(Opart + (size_t)SEQ * HID))[i];
  float l = Lpart[(size_t)head * SEQ + row] + Lpart[(size_t)(NH + head) * SEQ + row];
  float rl = 1.0f / l;
  short4 o;
  o.x = f2bf((a.x + b.x) * rl);
  o.y = f2bf((a.y + b.y) * rl);
  o.z = f2bf((a.z + b.z) * rl);
  o.w = f2bf((a.w + b.w) * rl);
  ((short4*)attn)[i] = o;
}

extern "C" void kernel_launch(void* const* d_in, const int* in_sizes, int n_in,
                              void* d_out, int out_size, void* d_ws, size_t ws_size,
                              hipStream_t stream) {
  const float* x      = (const float*)d_in[0];
  const float* ropec  = (const float*)d_in[1];
  const float* ropes  = (const float*)d_in[2];
  const float* n0w    = (const float*)d_in[3];
  const float* n0b    = (const float*)d_in[4];
  const float* n1w    = (const float*)d_in[5];
  const float* n1b    = (const float*)d_in[6];
  const float* wqkv_w = (const float*)d_in[7];
  const float* wqkv_b = (const float*)d_in[8];
  const float* wo_w   = (const float*)d_in[9];
  const float* wo_b   = (const float*)d_in[10];
  const float* up_w   = (const float*)d_in[11];
  const float* up_b   = (const float*)d_in[12];
  const float* down_w = (const float*)d_in[13];
  const float* down_b = (const float*)d_in[14];
  const int*   offs   = (const int*)d_in[15];
  float* out = (float*)d_out;

  char* p = (char*)d_ws;
  auto alloc = [&](size_t bytes) {
    char* r = p;
    p += (bytes + 255) & ~(size_t)255;
    return r;
  };
  short* wqkv_bf = (short*)alloc((size_t)3072 * 1024 * 2);
  short* wo_bf   = (short*)alloc((size_t)1024 * 1024 * 2);
  short* up_bf   = (short*)alloc((size_t)4096 * 1024 * 2);
  short* down_bf = (short*)alloc((size_t)4096 * 1024 * 2);
  short* h0      = (short*)alloc((size_t)2048 * 1024 * 2);
  float* qkv     = (float*)alloc((size_t)2048 * 3072 * 4);
  short* Qh      = (short*)alloc((size_t)2048 * 1024 * 2);
  short* Kh      = (short*)alloc((size_t)2048 * 1024 * 2);
  short* Vt      = (short*)alloc((size_t)2048 * 1024 * 2);
  short* attn    = (short*)alloc((size_t)2048 * 1024 * 2);
  float* x1      = (float*)alloc((size_t)2048 * 1024 * 4);
  short* h1      = (short*)alloc((size_t)2048 * 1024 * 2);
  short* u       = (short*)alloc((size_t)2048 * 4096 * 2);

  // attention fp32 partials alias the dead qkv buffer (24MB >= 16.25MB)
  float* Opart = qkv;
  float* Lpart = qkv + (size_t)2 * SEQ * HID;

  cvt_bf16_kernel<<<3072, 256, 0, stream>>>(wqkv_w, wqkv_bf, 3072 * 1024 / 4);
  cvt_bf16_kernel<<<1024, 256, 0, stream>>>(wo_w, wo_bf, 1024 * 1024 / 4);
  cvt_bf16_kernel<<<4096, 256, 0, stream>>>(up_w, up_bf, 4096 * 1024 / 4);
  cvt_bf16_kernel<<<4096, 256, 0, stream>>>(down_w, down_bf, 4096 * 1024 / 4);

  ln_kernel<<<2048, 256, 0, stream>>>(x, n0w, n0b, h0);
  gemm_bt_kernel<0><<<dim3(24, 16), 256, 0, stream>>>(h0, wqkv_bf, wqkv_b, nullptr, qkv, 2048, 3072, 1024);
  rope_qk_kernel<<<8192, 256, 0, stream>>>(qkv, ropec, ropes, Qh, Kh);
  vtrans_kernel<<<dim3(32, 16), 256, 0, stream>>>(qkv, Vt);
  attn_kernel<<<dim3(32, 16, 2), 256, 0, stream>>>(Qh, Kh, Vt, offs, Opart, Lpart);
  attn_merge_kernel<<<2048, 256, 0, stream>>>(Opart, Lpart, attn);
  gemm_bt_kernel<1><<<dim3(8, 16), 256, 0, stream>>>(attn, wo_bf, wo_b, x, x1, 2048, 1024, 1024);
  ln_kernel<<<2048, 256, 0, stream>>>(x1, n1w, n1b, h1);
  gemm_bt_kernel<2><<<dim3(32, 16), 256, 0, stream>>>(h1, up_bf, up_b, nullptr, u, 2048, 4096, 1024);
  gemm_bt_kernel<1><<<dim3(8, 16), 256, 0, stream>>>(u, down_bf, down_b, x1, out, 2048, 1024, 4096);
}

// Round 3
// 321.943 us; speedup vs baseline: 1.3443x; 1.1372x over previous
//
#include <hip/hip_runtime.h>
#include <hip/hip_bf16.h>
#include <math.h>

#define SEQ 2048
#define HID 1024
#define NH 16
#define HD 64

using f32x4  = __attribute__((ext_vector_type(4))) float;
using bf16x8 = __attribute__((ext_vector_type(8))) short;

union U8 { unsigned int u[4]; bf16x8 v; short s[8]; };

__device__ __forceinline__ short f2bf(float f) {
  unsigned int x = __float_as_uint(f);
  unsigned int r = (x + 0x7fffu + ((x >> 16) & 1u)) >> 16;
  return (short)(r & 0xffffu);
}

__device__ __forceinline__ unsigned int pkbf(float a, float b) {
  return ((unsigned int)(unsigned short)f2bf(a)) |
         (((unsigned int)(unsigned short)f2bf(b)) << 16);
}

__device__ __forceinline__ float bf2f_lo(unsigned int u) {
  return __uint_as_float((u & 0xffffu) << 16);
}
__device__ __forceinline__ float bf2f_hi(unsigned int u) {
  return __uint_as_float(u & 0xffff0000u);
}

__device__ __forceinline__ void async_cp16(const void* g, void* l) {
  __builtin_amdgcn_global_load_lds(
      (__attribute__((address_space(1))) void*)(g),
      (__attribute__((address_space(3))) void*)(l), 16, 0, 0);
}

// ---------------- fp32 -> bf16 weight conversion ----------------
__global__ void cvt_bf16_kernel(const float* __restrict__ in, short* __restrict__ out, int n4) {
  int i = blockIdx.x * blockDim.x + threadIdx.x;
  if (i < n4) {
    float4 v = ((const float4*)in)[i];
    short4 o;
    o.x = f2bf(v.x); o.y = f2bf(v.y); o.z = f2bf(v.z); o.w = f2bf(v.w);
    ((short4*)out)[i] = o;
  }
}

// ---------------- LayerNorm (row per block) ----------------
__global__ __launch_bounds__(256) void ln_kernel(const float* __restrict__ x,
    const float* __restrict__ w, const float* __restrict__ b, short* __restrict__ out) {
  int row = blockIdx.x;
  int tid = threadIdx.x;
  float4 v = ((const float4*)(x + (size_t)row * HID))[tid];
  float s  = v.x + v.y + v.z + v.w;
  float s2 = v.x*v.x + v.y*v.y + v.z*v.z + v.w*v.w;
#pragma unroll
  for (int o = 32; o >= 1; o >>= 1) {
    s  += __shfl_xor(s,  o);
    s2 += __shfl_xor(s2, o);
  }
  __shared__ float red[8];
  int wv = tid >> 6;
  if ((tid & 63) == 0) { red[wv] = s; red[4 + wv] = s2; }
  __syncthreads();
  float ts  = red[0] + red[1] + red[2] + red[3];
  float ts2 = red[4] + red[5] + red[6] + red[7];
  float mean = ts * (1.0f / HID);
  float var  = ts2 * (1.0f / HID) - mean * mean;
  float rs = rsqrtf(var + 1e-5f);
  float4 wv4 = ((const float4*)w)[tid];
  float4 bv4 = ((const float4*)b)[tid];
  short4 o;
  o.x = f2bf((v.x - mean) * rs * wv4.x + bv4.x);
  o.y = f2bf((v.y - mean) * rs * wv4.y + bv4.y);
  o.z = f2bf((v.z - mean) * rs * wv4.z + bv4.z);
  o.w = f2bf((v.w - mean) * rs * wv4.w + bv4.w);
  ((short4*)(out + (size_t)row * HID))[tid] = o;
}

// ---------------- RoPE on q,k (bf16 in) + split to (head, seq, hd) bf16 ------
__global__ void rope_qk_kernel(const short* __restrict__ qkvb,
    const float* __restrict__ cosb, const float* __restrict__ sinb,
    short* __restrict__ Qh, short* __restrict__ Kh) {
  int tid = blockIdx.x * blockDim.x + threadIdx.x;  // s*1024 + j*512 + h*32 + i
  int s   = tid >> 10;
  int r   = tid & 1023;
  int j   = r >> 9;
  int rem = r & 511;
  int h   = rem >> 5;
  int i   = rem & 31;
  int d   = i * 2;
  unsigned int u = *(const unsigned int*)(qkvb + (size_t)s * 3072 + j * 1024 + h * 64 + d);
  float a = bf2f_lo(u), b = bf2f_hi(u);
  float c  = cosb[s * 32 + i];
  float sn = sinb[s * 32 + i];
  unsigned int o = pkbf(a * c - b * sn, a * sn + b * c);
  short* dst = (j == 0 ? Qh : Kh) + ((size_t)h * SEQ + s) * HD + d;
  *(unsigned int*)dst = o;
}

// ---------------- V transpose (bf16 in) to (head, hd, seq) ----------------
__global__ __launch_bounds__(256) void vtrans_kernel(const short* __restrict__ qkvb,
                                                     short* __restrict__ Vt) {
  __shared__ short tile[64 * 72];  // pad 72 (144B rows, 16B-aligned chunks)
  int s0   = blockIdx.x * 64;
  int head = blockIdx.y;
  int tid  = threadIdx.x;
#pragma unroll
  for (int p = 0; p < 2; p++) {
    int seg = p * 256 + tid;
    int row = seg >> 3;
    int c8  = seg & 7;
    bf16x8 v = *(const bf16x8*)(qkvb + (size_t)(s0 + row) * 3072 + 2048 + head * 64 + c8 * 8);
    *(bf16x8*)(tile + row * 72 + c8 * 8) = v;
  }
  __syncthreads();
#pragma unroll
  for (int p = 0; p < 2; p++) {
    int seg = p * 256 + tid;
    int d   = seg >> 3;
    int sc  = seg & 7;
    U8 o;
#pragma unroll
    for (int j = 0; j < 8; j++) o.s[j] = tile[(sc * 8 + j) * 72 + d];
    *(bf16x8*)(Vt + ((size_t)head * HD + d) * SEQ + s0 + sc * 8) = o.v;
  }
}

// ---------------- GEMM: C(MxN) = A(MxK) * B(NxK)^T, bf16 MFMA ----------------
// EPI 1: float out = acc + bias + resid
// EPI 2: bf16 out  = gelu_tanh(acc + bias)
// EPI 3: bf16 out  = acc + bias
// EPI 4: float partial, no bias; A/B advance by z*Klen, out by z*M*N (split-K)
template <int EPI>
__global__ __launch_bounds__(256) void gemm_bt_kernel(
    const short* __restrict__ A, const short* __restrict__ B,
    const float* __restrict__ bias, const float* __restrict__ resid,
    void* __restrict__ outp, int M, int N, int Klen, int Kstride) {
  __shared__ __attribute__((aligned(16))) short Alds[128 * 32];
  __shared__ __attribute__((aligned(16))) short Blds[128 * 32];
  int tid = threadIdx.x;
  int w    = tid >> 6;
  int lane = tid & 63;
  int lcol  = lane & 15;
  int lhalf = lane >> 4;
  int m0 = blockIdx.y * 128;
  int n0 = blockIdx.x * 128;
  int z  = blockIdx.z;
  const short* Ap = A + (size_t)z * Klen;
  const short* Bp = B + (size_t)z * Klen;
  int wm = (w & 1) * 64;
  int wn = (w >> 1) * 64;
  f32x4 acc[4][4];
#pragma unroll
  for (int i = 0; i < 4; i++)
#pragma unroll
    for (int j = 0; j < 4; j++) acc[i][j] = (f32x4){0.f, 0.f, 0.f, 0.f};

  for (int k0 = 0; k0 < Klen; k0 += 32) {
#pragma unroll
    for (int p = 0; p < 2; p++) {
      int seg = p * 256 + tid;
      async_cp16(Ap + (size_t)(m0 + (seg >> 2)) * Kstride + k0 + (seg & 3) * 8,
                 Alds + p * 2048 + w * 512);
      async_cp16(Bp + (size_t)(n0 + (seg >> 2)) * Kstride + k0 + (seg & 3) * 8,
                 Blds + p * 2048 + w * 512);
    }
    __syncthreads();
    bf16x8 af[4], bfr[4];
#pragma unroll
    for (int i = 0; i < 4; i++)
      af[i] = *(const bf16x8*)(Alds + (wm + i * 16 + lcol) * 32 + lhalf * 8);
#pragma unroll
    for (int j = 0; j < 4; j++)
      bfr[j] = *(const bf16x8*)(Blds + (wn + j * 16 + lcol) * 32 + lhalf * 8);
#pragma unroll
    for (int i = 0; i < 4; i++)
#pragma unroll
      for (int j = 0; j < 4; j++)
        acc[i][j] = __builtin_amdgcn_mfma_f32_16x16x32_bf16(af[i], bfr[j], acc[i][j], 0, 0, 0);
    __syncthreads();
  }

  float* outf = (float*)outp + (EPI == 4 ? (size_t)z * M * N : 0);
#pragma unroll
  for (int i = 0; i < 4; i++) {
#pragma unroll
    for (int j = 0; j < 4; j++) {
#pragma unroll
      for (int r = 0; r < 4; r++) {
        int row = m0 + wm + i * 16 + lhalf * 4 + r;
        int col = n0 + wn + j * 16 + lcol;
        float v = acc[i][j][r];
        if (EPI != 4) v += bias[col];
        if (EPI == 1) v += resid[(size_t)row * N + col];
        if (EPI == 2) {
          float t = 0.7978845608028654f * (v + 0.044715f * v * v * v);
          v = 0.5f * v * (1.0f + tanhf(t));
          ((short*)outp)[(size_t)row * N + col] = f2bf(v);
        } else if (EPI == 3) {
          ((short*)outp)[(size_t)row * N + col] = f2bf(v);
        } else {
          outf[(size_t)row * N + col] = v;
        }
      }
    }
  }
}

// ---------------- Attention (single-pass exp, segment bias) ----------------
__global__ __launch_bounds__(256) void attn_kernel(
    const short* __restrict__ Qh, const short* __restrict__ Kh,
    const short* __restrict__ Vt, const int* __restrict__ offs,
    float* __restrict__ Opart, float* __restrict__ Lpart) {
  __shared__ __attribute__((aligned(16))) short Klds[64 * 64];
  __shared__ __attribute__((aligned(16))) short Vlds[64 * 64];
  __shared__ __attribute__((aligned(16))) unsigned int Plds[4][16 * 34];
  int head = blockIdx.y;
  int q0   = blockIdx.x * 64;
  int z    = blockIdx.z;
  int tid  = threadIdx.x;
  int w    = tid >> 6;
  int lane = tid & 63;
  int lcol = lane & 15;
  int h    = lane >> 4;

  int o0 = offs[0], o1 = offs[1], o2 = offs[2], o3 = offs[3], o4 = offs[4];
  int qrow = q0 + w * 16 + lcol;
  int sq = (qrow >= o1) + (qrow >= o2) + (qrow >= o3);
  int lo = sq == 0 ? o0 : (sq == 1 ? o1 : (sq == 2 ? o2 : o3));
  int hi = sq == 0 ? o1 : (sq == 1 ? o2 : (sq == 2 ? o3 : o4));

  const short* qb = Qh + ((size_t)head * SEQ + qrow) * HD + h * 8;
  bf16x8 qf0 = *(const bf16x8*)(qb);
  bf16x8 qf1 = *(const bf16x8*)(qb + 32);

  bf16x8 ones;
#pragma unroll
  for (int i = 0; i < 8; i++) ones[i] = 0x3F80;

  f32x4 o_acc[4];
#pragma unroll
  for (int nt = 0; nt < 4; nt++) o_acc[nt] = (f32x4){0.f, 0.f, 0.f, 0.f};
  f32x4 acc_l = (f32x4){0.f, 0.f, 0.f, 0.f};

  int tbeg = z * 1024;
  for (int t0 = tbeg; t0 < tbeg + 1024; t0 += 64) {
#pragma unroll
    for (int p = 0; p < 2; p++) {
      int seg = p * 256 + tid;
      int row = seg >> 3;
      int g   = (seg & 7) ^ (row & 7);
      async_cp16(Kh + ((size_t)head * SEQ + t0 + row) * HD + g * 8,
                 Klds + p * 2048 + w * 512);
      async_cp16(Vt + ((size_t)head * HD + row) * SEQ + t0 + g * 8,
                 Vlds + p * 2048 + w * 512);
    }
    __syncthreads();

#pragma unroll
    for (int n = 0; n < 4; n++) {
      int krow = n * 16 + lcol;
      const short* ka = Klds + krow * 64;
      bf16x8 kf0 = *(const bf16x8*)(ka + ((h ^ (lcol & 7)) * 8));
      bf16x8 kf1 = *(const bf16x8*)(ka + (((4 + h) ^ (lcol & 7)) * 8));
      f32x4 sacc = (f32x4){0.f, 0.f, 0.f, 0.f};
      sacc = __builtin_amdgcn_mfma_f32_16x16x32_bf16(kf0, qf0, sacc, 0, 0, 0);
      sacc = __builtin_amdgcn_mfma_f32_16x16x32_bf16(kf1, qf1, sacc, 0, 0, 0);
      float pv[4];
#pragma unroll
      for (int r = 0; r < 4; r++) {
        int key = t0 + n * 16 + h * 4 + r;
        float bias = (key >= lo && key < hi) ? -1.0f : -2.0f;
        pv[r] = __expf(fmaf(sacc[r], 0.125f, bias));
      }
      uint2 pw;
      pw.x = pkbf(pv[0], pv[1]);
      pw.y = pkbf(pv[2], pv[3]);
      *(uint2*)&Plds[w][lcol * 34 + n * 8 + h * 2] = pw;
    }

#pragma unroll
    for (int kc = 0; kc < 2; kc++) {
      int base = lcol * 34 + kc * 16 + h * 4;
      uint2 a = *(const uint2*)&Plds[w][base];
      uint2 b = *(const uint2*)&Plds[w][base + 2];
      U8 pu;
      pu.u[0] = a.x; pu.u[1] = a.y; pu.u[2] = b.x; pu.u[3] = b.y;
#pragma unroll
      for (int nt = 0; nt < 4; nt++) {
        int vrow = nt * 16 + lcol;
        bf16x8 vf = *(const bf16x8*)(Vlds + vrow * 64 + (((kc * 4 + h) ^ (lcol & 7)) * 8));
        o_acc[nt] = __builtin_amdgcn_mfma_f32_16x16x32_bf16(vf, pu.v, o_acc[nt], 0, 0, 0);
      }
      acc_l = __builtin_amdgcn_mfma_f32_16x16x32_bf16(ones, pu.v, acc_l, 0, 0, 0);
    }
    __syncthreads();
  }

  float* op = Opart + (size_t)z * SEQ * HID + (size_t)qrow * HID + head * HD + h * 4;
#pragma unroll
  for (int nt = 0; nt < 4; nt++)
    *(f32x4*)(op + nt * 16) = o_acc[nt];
  if (lane < 16)
    Lpart[((size_t)z * NH + head) * SEQ + qrow] = acc_l[0];
}

__global__ __launch_bounds__(256) void attn_merge_kernel(
    const float* __restrict__ Opart, const float* __restrict__ Lpart,
    short* __restrict__ attn) {
  int i = blockIdx.x * blockDim.x + threadIdx.x;
  int col4 = i & 255;
  int row  = i >> 8;
  int head = col4 >> 4;
  float4 a = ((const float4*)Opart)[i];
  float4 b = ((const float4*)(Opart + (size_t)SEQ * HID))[i];
  float l = Lpart[(size_t)head * SEQ + row] + Lpart[(size_t)(NH + head) * SEQ + row];
  float rl = 1.0f / l;
  short4 o;
  o.x = f2bf((a.x + b.x) * rl);
  o.y = f2bf((a.y + b.y) * rl);
  o.z = f2bf((a.z + b.z) * rl);
  o.w = f2bf((a.w + b.w) * rl);
  ((short4*)attn)[i] = o;
}

// ------- split-K merge + bias + residual + LayerNorm (row per block) -------
__global__ __launch_bounds__(256) void merge_ln_kernel(
    const float* __restrict__ part, const float* __restrict__ bias,
    const float* __restrict__ resid, const float* __restrict__ w,
    const float* __restrict__ b, float* __restrict__ x1, short* __restrict__ h1) {
  int row = blockIdx.x;
  int tid = threadIdx.x;
  size_t idx = (size_t)row * HID / 4 + tid;
  float4 v = ((const float4*)part)[idx];
#pragma unroll
  for (int z = 1; z < 4; z++) {
    float4 q = ((const float4*)part)[(size_t)z * SEQ * HID / 4 + idx];
    v.x += q.x; v.y += q.y; v.z += q.z; v.w += q.w;
  }
  float4 bi = ((const float4*)bias)[tid];
  float4 rs4 = ((const float4*)(resid + (size_t)row * HID))[tid];
  v.x += bi.x + rs4.x; v.y += bi.y + rs4.y; v.z += bi.z + rs4.z; v.w += bi.w + rs4.w;
  ((float4*)(x1 + (size_t)row * HID))[tid] = v;
  float s  = v.x + v.y + v.z + v.w;
  float s2 = v.x*v.x + v.y*v.y + v.z*v.z + v.w*v.w;
#pragma unroll
  for (int o = 32; o >= 1; o >>= 1) {
    s  += __shfl_xor(s,  o);
    s2 += __shfl_xor(s2, o);
  }
  __shared__ float red[8];
  int wv = tid >> 6;
  if ((tid & 63) == 0) { red[wv] = s; red[4 + wv] = s2; }
  __syncthreads();
  float ts  = red[0] + red[1] + red[2] + red[3];
  float ts2 = red[4] + red[5] + red[6] + red[7];
  float mean = ts * (1.0f / HID);
  float var  = ts2 * (1.0f / HID) - mean * mean;
  float rsq = rsqrtf(var + 1e-5f);
  float4 wv4 = ((const float4*)w)[tid];
  float4 bv4 = ((const float4*)b)[tid];
  short4 o;
  o.x = f2bf((v.x - mean) * rsq * wv4.x + bv4.x);
  o.y = f2bf((v.y - mean) * rsq * wv4.y + bv4.y);
  o.z = f2bf((v.z - mean) * rsq * wv4.z + bv4.z);
  o.w = f2bf((v.w - mean) * rsq * wv4.w + bv4.w);
  ((short4*)(h1 + (size_t)row * HID))[tid] = o;
}

// ------- split-K merge + bias + residual -> fp32 out -------
__global__ __launch_bounds__(256) void merge_bias_kernel(
    const float* __restrict__ part, const float* __restrict__ bias,
    const float* __restrict__ resid, float* __restrict__ out) {
  int i = blockIdx.x * blockDim.x + threadIdx.x;  // float4 index
  int col4 = i & 255;
  float4 v = ((const float4*)part)[i];
#pragma unroll
  for (int z = 1; z < 4; z++) {
    float4 q = ((const float4*)part)[(size_t)z * SEQ * HID / 4 + i];
    v.x += q.x; v.y += q.y; v.z += q.z; v.w += q.w;
  }
  float4 bi = ((const float4*)bias)[col4];
  float4 rs = ((const float4*)resid)[i];
  float4 o;
  o.x = v.x + bi.x + rs.x;
  o.y = v.y + bi.y + rs.y;
  o.z = v.z + bi.z + rs.z;
  o.w = v.w + bi.w + rs.w;
  ((float4*)out)[i] = o;
}

extern "C" void kernel_launch(void* const* d_in, const int* in_sizes, int n_in,
                              void* d_out, int out_size, void* d_ws, size_t ws_size,
                              hipStream_t stream) {
  const float* x      = (const float*)d_in[0];
  const float* ropec  = (const float*)d_in[1];
  const float* ropes  = (const float*)d_in[2];
  const float* n0w    = (const float*)d_in[3];
  const float* n0b    = (const float*)d_in[4];
  const float* n1w    = (const float*)d_in[5];
  const float* n1b    = (const float*)d_in[6];
  const float* wqkv_w = (const float*)d_in[7];
  const float* wqkv_b = (const float*)d_in[8];
  const float* wo_w   = (const float*)d_in[9];
  const float* wo_b   = (const float*)d_in[10];
  const float* up_w   = (const float*)d_in[11];
  const float* up_b   = (const float*)d_in[12];
  const float* down_w = (const float*)d_in[13];
  const float* down_b = (const float*)d_in[14];
  const int*   offs   = (const int*)d_in[15];
  float* out = (float*)d_out;

  char* base = (char*)d_ws;
  // ---- static layout with lifetime-based aliasing (peak 88.3 MB) ----
  short* wqkv_bf = (short*)(base + 0);           //  6.0 MB, whole run
  short* wo_bf   = (short*)(base + 6291456);     //  2.0 MB, whole run
  short* up_bf   = (short*)(base + 8388608);     //  8.0 MB, whole run
  short* down_bf = (short*)(base + 16777216);    //  8.0 MB, whole run
  short* h0      = (short*)(base + 25165824);    //  4.0 MB, dead after qkv gemm
  short* qkv_bf  = (short*)(base + 29360128);    // 12.6 MB, dead after rope/vtrans
  short* Qh      = (short*)(base + 41943040);    //  4.0 MB, dead after attn
  short* Kh      = (short*)(base + 46137344);    //  4.0 MB, dead after attn
  short* Vt      = (short*)(base + 50331648);    //  4.0 MB, dead after attn
  float* Apart   = (float*)(base + 54525952);    // 16.8 MB, dead after attn_merge
  float* Lpart   = (float*)(base + 71303168);    //  0.3 MB, dead after attn_merge
  short* attn    = (short*)(base + 71565312);    //  4.0 MB, dead after wo gemm
  float* x1      = (float*)(base + 75759616);    //  8.0 MB, live to end
  short* h1      = (short*)(base + 84148224);    //  4.0 MB, dead after up gemm
  // wo split-K partials: reuse h0..Apart region (dead by then)
  float* wopart  = (float*)(base + 25165824);    // 33.6 MB -> ends 58.7 MB
  // gelu output: reuse h0/qkv region (dead after merge_ln consumed wopart)
  short* u       = (short*)(base + 25165824);    // 16.8 MB -> ends 41.9 MB
  // down split-K partials: after Qh..attn dead
  float* dnpart  = (float*)(base + 41943040);    // 33.6 MB -> ends 75.5 MB (< x1)

  cvt_bf16_kernel<<<3072, 256, 0, stream>>>(wqkv_w, wqkv_bf, 3072 * 1024 / 4);
  cvt_bf16_kernel<<<1024, 256, 0, stream>>>(wo_w, wo_bf, 1024 * 1024 / 4);
  cvt_bf16_kernel<<<4096, 256, 0, stream>>>(up_w, up_bf, 4096 * 1024 / 4);
  cvt_bf16_kernel<<<4096, 256, 0, stream>>>(down_w, down_bf, 4096 * 1024 / 4);

  ln_kernel<<<2048, 256, 0, stream>>>(x, n0w, n0b, h0);
  gemm_bt_kernel<3><<<dim3(24, 16), 256, 0, stream>>>(h0, wqkv_bf, wqkv_b, nullptr,
                                                      qkv_bf, 2048, 3072, 1024, 1024);
  rope_qk_kernel<<<8192, 256, 0, stream>>>(qkv_bf, ropec, ropes, Qh, Kh);
  vtrans_kernel<<<dim3(32, 16), 256, 0, stream>>>(qkv_bf, Vt);
  attn_kernel<<<dim3(32, 16, 2), 256, 0, stream>>>(Qh, Kh, Vt, offs, Apart, Lpart);
  attn_merge_kernel<<<2048, 256, 0, stream>>>(Apart, Lpart, attn);
  // wo: M=2048 N=1024 K=1024, split-K=4 (Klen=256) -> 512 blocks
  gemm_bt_kernel<4><<<dim3(8, 16, 4), 256, 0, stream>>>(attn, wo_bf, nullptr, nullptr,
                                                        wopart, 2048, 1024, 256, 1024);
  merge_ln_kernel<<<2048, 256, 0, stream>>>(wopart, wo_b, x, n1w, n1b, x1, h1);
  gemm_bt_kernel<2><<<dim3(32, 16), 256, 0, stream>>>(h1, up_bf, up_b, nullptr,
                                                      u, 2048, 4096, 1024, 1024);
  // down: M=2048 N=1024 K=4096, split-K=4 (Klen=1024) -> 512 blocks
  gemm_bt_kernel<4><<<dim3(8, 16, 4), 256, 0, stream>>>(u, down_bf, nullptr, nullptr,
                                                        dnpart, 2048, 1024, 1024, 4096);
  merge_bias_kernel<<<2048, 256, 0, stream>>>(dnpart, down_b, x1, out);
}